// Round 19
// baseline (201.874 us; speedup 1.0000x reference)
//
#include <hip/hip_runtime.h>
#include <cstdint>
#include <cstddef>

#define SQ 2048
#define NH 16
#define DH 64
#define HIDN 1024

typedef __attribute__((ext_vector_type(8))) short bf16x8;
typedef __attribute__((ext_vector_type(4))) float f32x4;
typedef __attribute__((ext_vector_type(2))) unsigned u32x2;

__device__ inline short f2b(float x) {
  union { float f; unsigned u; } un; un.f = x;
  unsigned r = un.u + 0x7fffu + ((un.u >> 16) & 1u);
  return (short)(r >> 16);
}

__device__ inline unsigned cvt_pk(float lo, float hi) {
  unsigned r;
  asm("v_cvt_pk_bf16_f32 %0, %1, %2" : "=v"(r) : "v"(lo), "v"(hi));
  return r;
}

__device__ inline f32x4 mfma16(u32x2 a, u32x2 b, f32x4 c) {
  asm("v_mfma_f32_16x16x16_bf16 %0, %1, %2, %0" : "+v"(c) : "v"(a), "v"(b));
  return c;
}

__device__ inline void gl_lds16(const void* g, void* l) {
  __builtin_amdgcn_global_load_lds(
      (const __attribute__((address_space(1))) void*)g,
      (__attribute__((address_space(3))) void*)l, 16, 0, 0);
}

// ---------------- merged prep: qkv->bf16 | wconv x4 | padk | lam ----------------
// flat grid 20497: [0,12288) qkv, [12288,20480) wconv, [20480,20496) padk, 20496 lam.
__global__ __launch_bounds__(256) void prep(
    const float4* __restrict__ q4, const float4* __restrict__ k4,
    const float4* __restrict__ v4, short4* __restrict__ qkvb,
    const float* __restrict__ Wq, const float* __restrict__ Wk,
    const float* __restrict__ Wv, const float* __restrict__ Wo,
    short* __restrict__ WqT, short* __restrict__ WkT,
    short* __restrict__ WvT, short* __restrict__ WoT,
    const float* __restrict__ mask, float* __restrict__ padl2,
    const float* __restrict__ lq1, const float* __restrict__ lq2,
    const float* __restrict__ lk1, const float* __restrict__ lk2,
    float* __restrict__ lam) {
  __shared__ float t[32][33];
  const int bid = blockIdx.x;
  const int tid = threadIdx.x;

  if (bid < 12288) {  // ---- qkv f32 -> bf16 ----
    int i = bid * 256 + tid;
    const float4* src = (i < 1048576) ? q4 : ((i < 2097152) ? k4 : v4);
    float4 val = src[i & 1048575];
    short4 o;
    o.x = f2b(val.x); o.y = f2b(val.y); o.z = f2b(val.z); o.w = f2b(val.w);
    qkvb[i] = o;
    return;
  }
  if (bid < 20480) {  // ---- wconv: W[K][N] f32 -> Wt[N][K] bf16 ----
    int wq = bid - 12288;
    int z = wq >> 11, rem = wq & 2047;
    int nx = rem & 63, ky = rem >> 6;
    int N = (z < 2) ? 2048 : 1024;
    if (nx * 32 >= N) return;  // block-uniform
    const float* W = (z == 0) ? Wq : (z == 1) ? Wk : (z == 2) ? Wv : Wo;
    short* Wt = (z == 0) ? WqT : (z == 1) ? WkT : (z == 2) ? WvT : WoT;
    const int K = 1024;
    int n0 = nx * 32, k0 = ky * 32;
    int tx = tid & 31, ty = tid >> 5;
#pragma unroll
    for (int r = 0; r < 4; ++r)
      t[ty + r * 8][tx] = W[(size_t)(k0 + ty + r * 8) * N + n0 + tx];
    __syncthreads();
#pragma unroll
    for (int r = 0; r < 4; ++r)
      Wt[(size_t)(n0 + ty + r * 8) * K + k0 + tx] = f2b(t[tx][ty + r * 8]);
    return;
  }
  if (bid < 20496) {  // ---- padk ----
    int i = (bid - 20480) * 256 + tid;
    padl2[i] = (1.0f - mask[i]) * (-1.0e9f) * 1.44269504089f;
    return;
  }
  // ---- lambda scalar (wave 0 only) ----
  if (tid < 64) {
    float d1 = lq1[tid] * lk1[tid], d2 = lq2[tid] * lk2[tid];
#pragma unroll
    for (int x = 1; x < 64; x <<= 1) { d1 += __shfl_xor(d1, x); d2 += __shfl_xor(d2, x); }
    if (tid == 0) lam[0] = __expf(d1) - __expf(d2) + 0.8f;
  }
}

// ---- counted-vmcnt phase template: kk-split stage (2 chunks/thread/half) ----
#define STG(dst, srcp, kt, kk)                                                        \
  {                                                                                   \
    gl_lds16(srcp + (size_t)r0_ * 1024 + ((kt) << 6) + ((kk) << 5) + c0_,             \
             &dst[ch0_ << 3]);                                                        \
    gl_lds16(srcp + (size_t)r1_ * 1024 + ((kt) << 6) + ((kk) << 5) + c1_,             \
             &dst[ch1_ << 3]);                                                        \
  }

// ---------------- merged Q/K/V projection GEMMs, v3: counted-vmcnt phases ----------------
__global__ __launch_bounds__(256) void proj3(const short* __restrict__ Abase,
                                             const short* __restrict__ Btbase,
                                             short* __restrict__ QKout,
                                             short* __restrict__ Vtb) {
  __shared__ __align__(16) short As[2][2][128 * 32];
  __shared__ __align__(16) short Bs[2][2][128 * 32];
  const int bid = blockIdx.x;
  const int wk = (bid & 7) * 160 + (bid >> 3);  // bijective XCD chunk swizzle
  int z, my, nx;
  if (wk < 1024) { z = wk >> 9; int r = wk & 511; my = r >> 4; nx = r & 15; }
  else { z = 2; int r = wk - 1024; my = r >> 3; nx = r & 7; }

  const int tid = threadIdx.x;
  const int lane = tid & 63, w = tid >> 6;
  const int l15 = lane & 15, lhi = lane >> 4;
  const int wr = w >> 1, wc = w & 1;
  const int m0 = my * 128, n0 = nx * 128;

  const short* Ag = Abase + (size_t)z * 4194304 + (size_t)m0 * 1024;
  const short* Bg = Btbase + (size_t)z * 2097152 + (size_t)n0 * 1024;

  const int ch0_ = tid, ch1_ = tid + 256;
  const int r0_ = ch0_ >> 2, c0_ = (ch0_ & 3) << 3;
  const int r1_ = ch1_ >> 2, c1_ = (ch1_ & 3) << 3;

  f32x4 acc[4][4];
#pragma unroll
  for (int i = 0; i < 4; ++i)
#pragma unroll
    for (int j = 0; j < 4; ++j) acc[i][j] = (f32x4){0.f, 0.f, 0.f, 0.f};

  STG(As[0][0], Ag, 0, 0); STG(Bs[0][0], Bg, 0, 0);
  STG(As[0][1], Ag, 0, 1); STG(Bs[0][1], Bg, 0, 1);
  asm volatile("s_waitcnt vmcnt(4)" ::: "memory");
  __builtin_amdgcn_s_barrier();

  for (int kt = 0; kt < 16; ++kt) {
    const int buf = kt & 1;
#pragma unroll
    for (int kk = 0; kk < 2; ++kk) {
      const short* Ah = As[buf][kk];
      const short* Bh = Bs[buf][kk];
      bf16x8 af[4], bfr[4];
#pragma unroll
      for (int mi = 0; mi < 4; ++mi)
        af[mi] = *(const bf16x8*)&Ah[((wr * 64 + mi * 16 + l15) << 5) + (lhi << 3)];
#pragma unroll
      for (int ni = 0; ni < 4; ++ni)
        bfr[ni] = *(const bf16x8*)&Bh[((wc * 64 + ni * 16 + l15) << 5) + (lhi << 3)];
      if (kt < 15) {
        STG(As[buf ^ 1][kk], Ag, kt + 1, kk);
        STG(Bs[buf ^ 1][kk], Bg, kt + 1, kk);
      }
      __builtin_amdgcn_s_barrier();
      __builtin_amdgcn_s_setprio(1);
#pragma unroll
      for (int mi = 0; mi < 4; ++mi)
#pragma unroll
        for (int ni = 0; ni < 4; ++ni)
          acc[mi][ni] = __builtin_amdgcn_mfma_f32_16x16x32_bf16(af[mi], bfr[ni], acc[mi][ni], 0, 0, 0);
      __builtin_amdgcn_s_setprio(0);
      if (kt < 15) asm volatile("s_waitcnt vmcnt(4)" ::: "memory");
      else         asm volatile("s_waitcnt vmcnt(0)" ::: "memory");
      __builtin_amdgcn_s_barrier();
    }
  }

#pragma unroll
  for (int mi = 0; mi < 4; ++mi) {
#pragma unroll
    for (int ni = 0; ni < 4; ++ni) {
#pragma unroll
      for (int j = 0; j < 4; ++j) {
        int m = m0 + wr * 64 + mi * 16 + (lhi << 2) + j;
        int n = n0 + wc * 64 + ni * 16 + l15;
        float v = acc[mi][ni][j];
        int s = m & (SQ - 1), bb = m >> 11;
        if (z < 2) {
          int h = n >> 7, t = n & 127, path = t >> 6, tt = t & 63;
          (QKout + (size_t)z * 8388608)
              [((((size_t)(bb * NH + h) * 2 + path) * SQ + s) << 6) + tt] = f2b(v);
        } else {
          int h = n >> 6, t = n & 63;
          Vtb[(((size_t)(bb * NH + h) << 6) + t) * SQ + s] = f2b(v);
        }
      }
    }
  }
}

// ---------------- final GEMM, v3: counted-vmcnt phases ----------------
__global__ __launch_bounds__(256) void gemm_out(const short* __restrict__ A,
                                                const short* __restrict__ Bt,
                                                float* __restrict__ Cout) {
  __shared__ __align__(16) short As[2][2][128 * 32];
  __shared__ __align__(16) short Bs[2][2][128 * 32];
  const int bid = blockIdx.x;
  const int wk = (bid & 7) * 32 + (bid >> 3);
  const int my = wk >> 3, nx = wk & 7;

  const int tid = threadIdx.x;
  const int lane = tid & 63, w = tid >> 6;
  const int l15 = lane & 15, lhi = lane >> 4;
  const int wr = w >> 1, wc = w & 1;
  const int m0 = my * 128, n0 = nx * 128;

  const short* Ag = A + (size_t)m0 * 1024;
  const short* Bg = Bt + (size_t)n0 * 1024;

  const int ch0_ = tid, ch1_ = tid + 256;
  const int r0_ = ch0_ >> 2, c0_ = (ch0_ & 3) << 3;
  const int r1_ = ch1_ >> 2, c1_ = (ch1_ & 3) << 3;

  f32x4 acc[4][4];
#pragma unroll
  for (int i = 0; i < 4; ++i)
#pragma unroll
    for (int j = 0; j < 4; ++j) acc[i][j] = (f32x4){0.f, 0.f, 0.f, 0.f};

  STG(As[0][0], Ag, 0, 0); STG(Bs[0][0], Bg, 0, 0);
  STG(As[0][1], Ag, 0, 1); STG(Bs[0][1], Bg, 0, 1);
  asm volatile("s_waitcnt vmcnt(4)" ::: "memory");
  __builtin_amdgcn_s_barrier();

  for (int kt = 0; kt < 16; ++kt) {
    const int buf = kt & 1;
#pragma unroll
    for (int kk = 0; kk < 2; ++kk) {
      const short* Ah = As[buf][kk];
      const short* Bh = Bs[buf][kk];
      bf16x8 af[4], bfr[4];
#pragma unroll
      for (int mi = 0; mi < 4; ++mi)
        af[mi] = *(const bf16x8*)&Ah[((wr * 64 + mi * 16 + l15) << 5) + (lhi << 3)];
#pragma unroll
      for (int ni = 0; ni < 4; ++ni)
        bfr[ni] = *(const bf16x8*)&Bh[((wc * 64 + ni * 16 + l15) << 5) + (lhi << 3)];
      if (kt < 15) {
        STG(As[buf ^ 1][kk], Ag, kt + 1, kk);
        STG(Bs[buf ^ 1][kk], Bg, kt + 1, kk);
      }
      __builtin_amdgcn_s_barrier();
      __builtin_amdgcn_s_setprio(1);
#pragma unroll
      for (int mi = 0; mi < 4; ++mi)
#pragma unroll
        for (int ni = 0; ni < 4; ++ni)
          acc[mi][ni] = __builtin_amdgcn_mfma_f32_16x16x32_bf16(af[mi], bfr[ni], acc[mi][ni], 0, 0, 0);
      __builtin_amdgcn_s_setprio(0);
      if (kt < 15) asm volatile("s_waitcnt vmcnt(4)" ::: "memory");
      else         asm volatile("s_waitcnt vmcnt(0)" ::: "memory");
      __builtin_amdgcn_s_barrier();
    }
  }

#pragma unroll
  for (int mi = 0; mi < 4; ++mi)
#pragma unroll
    for (int ni = 0; ni < 4; ++ni)
#pragma unroll
      for (int j = 0; j < 4; ++j) {
        int m = m0 + wr * 64 + mi * 16 + (lhi << 2) + j;
        int n = n0 + wc * 64 + ni * 16 + l15;
        Cout[(size_t)m * 1024 + n] = acc[mi][ni][j];
      }
}

// ---------------- flash differential attention (v8, r10-exact) ----------------
__global__ __launch_bounds__(256) void diff_attn(
    const short* __restrict__ Qp, const short* __restrict__ Kp,
    const short* __restrict__ Vt, const float* __restrict__ padl2,
    const float* __restrict__ lamp, float* __restrict__ attn,
    float* __restrict__ part) {
  __shared__ __align__(16) short K1s[2][64 * 64];
  __shared__ __align__(16) short K2s[2][64 * 64];
  __shared__ __align__(16) short Vts[2][64 * 64];
  __shared__ float red[8];

  const int bid = blockIdx.x;
  const int rk = bid >> 5, bh = bid & 31;
  const int qtA = 31 - rk, qtB = rk;
  const int ntA = qtA + 1, ntT = ntA + qtB + 1;
  const int b = bh >> 4, h = bh & 15;
  const int tid = threadIdx.x, lane = tid & 63, w = tid >> 6;
  const int l15 = lane & 15, lhi = lane >> 4;
  const int sw7 = l15 & 7;
  const int u0 = (lhi ^ sw7) << 3, u1 = ((4 + lhi) ^ sw7) << 3;

  const float L2E = 1.44269504089f;
  const float slope = exp2f(-0.5f * (float)(h + 1));
  const float SC = 0.125f * L2E;
  const float sl2 = slope * L2E;

  f32x4 ck[4];
#pragma unroll
  for (int cf = 0; cf < 4; ++cf)
#pragma unroll
    for (int j = 0; j < 4; ++j)
      ck[cf][j] = sl2 * (float)(16 * cf + 4 * lhi + j);

  const short* Q1g = Qp + (((size_t)bh * 2 + 0) * SQ) * DH;
  const short* Q2g = Qp + (((size_t)bh * 2 + 1) * SQ) * DH;
  const short* K1g = Kp + (((size_t)bh * 2 + 0) * SQ) * DH;
  const short* K2g = Kp + (((size_t)bh * 2 + 1) * SQ) * DH;
  const short* Vtg = Vt + (size_t)bh * DH * SQ;
  const float* padb = padl2 + (b << 11);

  int ucf[4];
#pragma unroll
  for (int cf = 0; cf < 4; ++cf)
    ucf[cf] = (((2 * cf + (lhi >> 1)) ^ sw7) << 1) + (lhi & 1);

  const int sidx0 = tid, sidx1 = 256 + tid;
  const int srow0 = sidx0 >> 3, sus0 = ((sidx0 & 7) ^ (srow0 & 7)) << 3;
  const int srow1 = sidx1 >> 3, sus1 = ((sidx1 & 7) ^ (srow1 & 7)) << 3;

#define STAGE(buf, k0s)                                                          \
  {                                                                              \
    gl_lds16(K1g + (size_t)((k0s) + srow0) * DH + sus0, &K1s[buf][sidx0 << 3]);  \
    gl_lds16(K2g + (size_t)((k0s) + srow0) * DH + sus0, &K2s[buf][sidx0 << 3]);  \
    gl_lds16(Vtg + (size_t)srow0 * SQ + (k0s) + sus0, &Vts[buf][sidx0 << 3]);    \
    gl_lds16(K1g + (size_t)((k0s) + srow1) * DH + sus1, &K1s[buf][sidx1 << 3]);  \
    gl_lds16(K2g + (size_t)((k0s) + srow1) * DH + sus1, &K2s[buf][sidx1 << 3]);  \
    gl_lds16(Vtg + (size_t)srow1 * SQ + (k0s) + sus1, &Vts[buf][sidx1 << 3]);    \
  }

  int cur = 0;
  int itg = 0;
  STAGE(0, 0);
  asm volatile("s_waitcnt vmcnt(0)" ::: "memory");
  __builtin_amdgcn_s_barrier();

  const float lamv = lamp[0];

  for (int ph = 0; ph < 2; ++ph) {
    const int qt = ph ? qtB : qtA;
    const int nt = qt + 1;
    const int wq0 = qt * 64 + (w << 4);
    const int q = wq0 + l15;
    const float qb8 = sl2 * (float)q + 8.0f;  // fixed max 8 (log2 domain)

    bf16x8 aq[2][2];
#pragma unroll
    for (int kk = 0; kk < 2; ++kk) {
      aq[0][kk] = *(const bf16x8*)&Q1g[(size_t)q * DH + kk * 32 + lhi * 8];
      aq[1][kk] = *(const bf16x8*)&Q2g[(size_t)q * DH + kk * 32 + lhi * 8];
    }
    f32x4 cq[4];
#pragma unroll
    for (int cf = 0; cf < 4; ++cf)
#pragma unroll
      for (int j = 0; j < 4; ++j) cq[cf][j] = ck[cf][j] - qb8;

    f32x4 acc[2][4];
    float ll[2] = {0.f, 0.f};
#pragma unroll
    for (int p = 0; p < 2; ++p)
#pragma unroll
      for (int i = 0; i < 4; ++i) acc[p][i] = (f32x4){0.f, 0.f, 0.f, 0.f};

    for (int kt = 0; kt < nt; ++kt, ++itg) {
      const int k0 = kt << 6;
      int g = itg + 1;
      if (g < ntT) {
        int k0n = ((g < ntA) ? g : g - ntA) << 6;
        STAGE(cur ^ 1, k0n);
      }

      const float t0 = sl2 * (float)k0;
      f32x4 base4[4];
#pragma unroll
      for (int cf = 0; cf < 4; ++cf) {
        f32x4 p4 = *(const f32x4*)&padb[k0 + 16 * cf + 4 * lhi];
#pragma unroll
        for (int j = 0; j < 4; ++j) base4[cf][j] = cq[cf][j] + (t0 + p4[j]);
      }
      const bool diag = (kt == nt - 1);

      u32x2 pa[2][4];
#pragma unroll
      for (int p = 0; p < 2; ++p) {
        const short* Ks = (p == 0) ? K1s[cur] : K2s[cur];
        f32x4 sv[4];
#pragma unroll
        for (int cf = 0; cf < 4; ++cf) {
          int rb = (cf * 16 + l15) << 6;
          f32x4 z = (f32x4){0.f, 0.f, 0.f, 0.f};
          bf16x8 ka = *(const bf16x8*)&Ks[rb + u0];
          bf16x8 kb = *(const bf16x8*)&Ks[rb + u1];
          sv[cf] = __builtin_amdgcn_mfma_f32_16x16x32_bf16(ka, aq[p][0], z, 0, 0, 0);
          sv[cf] = __builtin_amdgcn_mfma_f32_16x16x32_bf16(kb, aq[p][1], sv[cf], 0, 0, 0);
        }
        float rsum = 0.f;
#pragma unroll
        for (int cf = 0; cf < 4; ++cf) {
          float pv[4];
#pragma unroll
          for (int j = 0; j < 4; ++j) pv[j] = sv[cf][j] * SC + base4[cf][j];
          if (diag) {
#pragma unroll
            for (int j = 0; j < 4; ++j) {
              int kc = k0 + 16 * cf + 4 * lhi + j;
              pv[j] = (kc > q) ? -1.0e9f : pv[j];
            }
          }
          float e0 = exp2f(pv[0]);
          float e1 = exp2f(pv[1]);
          float e2 = exp2f(pv[2]);
          float e3 = exp2f(pv[3]);
          rsum += (e0 + e1) + (e2 + e3);
          pa[p][cf][0] = cvt_pk(e0, e1);
          pa[p][cf][1] = cvt_pk(e2, e3);
        }
        ll[p] += rsum;
      }

      // PV: A = P (register-resident), B = V^T b64 fragments
#pragma unroll
      for (int df = 0; df < 4; ++df) {
        const u32x2* vrow = (const u32x2*)&Vts[cur][(df * 16 + l15) << 6];
#pragma unroll
        for (int cf = 0; cf < 4; ++cf) {
          u32x2 vb = vrow[ucf[cf]];
          acc[0][df] = mfma16(pa[0][cf], vb, acc[0][df]);
          acc[1][df] = mfma16(pa[1][cf], vb, acc[1][df]);
        }
      }

      asm volatile("s_waitcnt vmcnt(0)" ::: "memory");
      __builtin_amdgcn_s_barrier();
      cur ^= 1;
    }

#pragma unroll
    for (int p = 0; p < 2; ++p) {
      ll[p] += __shfl_xor(ll[p], 16);
      ll[p] += __shfl_xor(ll[p], 32);
    }
    float li1 = 1.0f / ll[0], li2 = lamv / ll[1];
    float li1b[4], li2b[4];
#pragma unroll
    for (int j = 0; j < 4; ++j) {
      li1b[j] = __shfl(li1, (lhi << 2) + j);
      li2b[j] = __shfl(li2, (lhi << 2) + j);
    }
    float lsum = 0.f, lsq = 0.f;
#pragma unroll
    for (int df = 0; df < 4; ++df)
#pragma unroll
      for (int j = 0; j < 4; ++j) {
        int qq = wq0 + (lhi << 2) + j;
        float o = acc[0][df][j] * li1b[j] - acc[1][df][j] * li2b[j];
        attn[((size_t)b * SQ + qq) * HIDN + (h << 6) + (df << 4) + l15] = o;
        lsum += o; lsq += o * o;
      }
#pragma unroll
    for (int x = 1; x < 64; x <<= 1) {
      lsum += __shfl_xor(lsum, x);
      lsq += __shfl_xor(lsq, x);
    }
    if (lane == 0) { red[w] = lsum; red[4 + w] = lsq; }
    __syncthreads();
    if (tid == 0) {
      part[((size_t)bh * 32 + qt) * 2] = red[0] + red[1] + red[2] + red[3];
      part[((size_t)bh * 32 + qt) * 2 + 1] = red[4] + red[5] + red[6] + red[7];
    }
  }
#undef STAGE
}

// ---------------- GN stats + apply -> bf16 X (stats_fin fused in) ----------------
// One block (256 thr) per row r. The 8 x 32-lane groups each reduce TWO bh
// entries (bhl, bhl+8) with the identical 32-lane xor-shuffle tree
// (bit-identical arithmetic to the old stats_fin).
__global__ __launch_bounds__(256) void gn_apply(const float* __restrict__ attn,
                                                const float* __restrict__ part,
                                                const float* __restrict__ gnw,
                                                const float* __restrict__ gnb,
                                                short* __restrict__ X) {
  __shared__ float smean[16], sinv[16];
  const int r = blockIdx.x;            // 0..4095 row of [B*SQ][1024]
  const int tid = threadIdx.x;
  const int bh_base = (r >> 11) << 4;  // 16 consecutive bh for this row

  {
    int grp = tid >> 5, i = tid & 31;  // 8 groups of 32 lanes
#pragma unroll
    for (int rep = 0; rep < 2; ++rep) {
      int bhl = grp + rep * 8;
      float s = part[((size_t)(bh_base + bhl) * 32 + i) * 2];
      float ss = part[((size_t)(bh_base + bhl) * 32 + i) * 2 + 1];
#pragma unroll
      for (int x = 1; x < 32; x <<= 1) { s += __shfl_xor(s, x); ss += __shfl_xor(ss, x); }
      if (i == 0) {
        float n = (float)(SQ * DH);
        float mean = s / n;
        float var = ss / n - mean * mean;
        smean[bhl] = mean;
        sinv[bhl] = rsqrtf(var + 1e-5f);
      }
    }
  }
  __syncthreads();

  size_t base = ((size_t)r << 10) + ((size_t)tid << 2);
  int c = tid << 2;
  int bhl = c >> 6;
  float mean = smean[bhl], inv = sinv[bhl];
  float4 a = *(const float4*)&attn[base];
  short4 o;
  o.x = f2b(((a.x - mean) * inv * gnw[c + 0] + gnb[c + 0]) * 0.2f);
  o.y = f2b(((a.y - mean) * inv * gnw[c + 1] + gnb[c + 1]) * 0.2f);
  o.z = f2b(((a.z - mean) * inv * gnw[c + 2] + gnb[c + 2]) * 0.2f);
  o.w = f2b(((a.w - mean) * inv * gnw[c + 3] + gnb[c + 3]) * 0.2f);
  *(short4*)&X[base] = o;
}

extern "C" void kernel_launch(void* const* d_in, const int* in_sizes, int n_in,
                              void* d_out, int out_size, void* d_ws, size_t ws_size,
                              hipStream_t stream) {
  const float* query = (const float*)d_in[0];
  const float* key = (const float*)d_in[1];
  const float* value = (const float*)d_in[2];
  const float* mask = (const float*)d_in[3];
  const float* Wq = (const float*)d_in[4];
  const float* Wk = (const float*)d_in[5];
  const float* Wv = (const float*)d_in[6];
  const float* Wo = (const float*)d_in[7];
  const float* lq1 = (const float*)d_in[8];
  const float* lq2 = (const float*)d_in[9];
  const float* lk1 = (const float*)d_in[10];
  const float* lk2 = (const float*)d_in[11];
  const float* gnw = (const float*)d_in[12];
  const float* gnb = (const float*)d_in[13];

  char* ws = (char*)d_ws;
  short* WqT = (short*)(ws + 0);          //  4 MiB   (WqT,WkT,WvT contiguous)
  short* WkT = (short*)(ws + 4194304);
  short* WvT = (short*)(ws + 8388608);
  short* WoT = (short*)(ws + 10485760);   //  2 MiB
  short* qb = (short*)(ws + 12582912);    //  8 MiB (qb,kb,vb contiguous)
  short* Qp = (short*)(ws + 37748736);    // 16 MiB (Qp,Kp contiguous)
  short* Kp = (short*)(ws + 54525952);
  short* Vtb = (short*)(ws + 71303168);   //  8 MiB
  float* attn = (float*)(ws + 12582912);  // 16 MiB, overlays qb+kb
  short* X = (short*)(ws + 29360128);     //  8 MiB, overlays vb
  float* part = (float*)(ws + 79691776);  // 16 KiB
  float* lam = (float*)(ws + 79708416);   //  4 B
  float* padl2 = (float*)(ws + 79708672); // 16 KiB

  prep<<<dim3(20497), 256, 0, stream>>>(
      (const float4*)query, (const float4*)key, (const float4*)value, (short4*)qb,
      Wq, Wk, Wv, Wo, WqT, WkT, WvT, WoT, mask, padl2, lq1, lq2, lk1, lk2, lam);

  proj3<<<dim3(1280), 256, 0, stream>>>(qb, WqT, Qp, Vtb);

  diff_attn<<<dim3(512), 256, 0, stream>>>(Qp, Kp, Vtb, padl2, lam, attn, part);
  gn_apply<<<4096, 256, 0, stream>>>(attn, part, gnw, gnb, X);
  gemm_out<<<dim3(256), 256, 0, stream>>>(X, WoT, (float*)d_out);
}

// Round 20
// 200.874 us; speedup vs baseline: 1.0050x; 1.0050x over previous
//
#include <hip/hip_runtime.h>
#include <cstdint>
#include <cstddef>

#define SQ 2048
#define NH 16
#define DH 64
#define HIDN 1024

typedef __attribute__((ext_vector_type(8))) short bf16x8;
typedef __attribute__((ext_vector_type(4))) float f32x4;
typedef __attribute__((ext_vector_type(2))) unsigned u32x2;

__device__ inline short f2b(float x) {
  union { float f; unsigned u; } un; un.f = x;
  unsigned r = un.u + 0x7fffu + ((un.u >> 16) & 1u);
  return (short)(r >> 16);
}

__device__ inline float b2f(short s) {
  union { unsigned u; float f; } un;
  un.u = ((unsigned)(unsigned short)s) << 16;
  return un.f;
}

__device__ inline unsigned cvt_pk(float lo, float hi) {
  unsigned r;
  asm("v_cvt_pk_bf16_f32 %0, %1, %2" : "=v"(r) : "v"(lo), "v"(hi));
  return r;
}

__device__ inline f32x4 mfma16(u32x2 a, u32x2 b, f32x4 c) {
  asm("v_mfma_f32_16x16x16_bf16 %0, %1, %2, %0" : "+v"(c) : "v"(a), "v"(b));
  return c;
}

__device__ inline void gl_lds16(const void* g, void* l) {
  __builtin_amdgcn_global_load_lds(
      (const __attribute__((address_space(1))) void*)g,
      (__attribute__((address_space(3))) void*)l, 16, 0, 0);
}

// ---------------- merged prep: qkv->bf16 | wconv x4 | padk | lam ----------------
// flat grid 20497: [0,12288) qkv, [12288,20480) wconv, [20480,20496) padk, 20496 lam.
__global__ __launch_bounds__(256) void prep(
    const float4* __restrict__ q4, const float4* __restrict__ k4,
    const float4* __restrict__ v4, short4* __restrict__ qkvb,
    const float* __restrict__ Wq, const float* __restrict__ Wk,
    const float* __restrict__ Wv, const float* __restrict__ Wo,
    short* __restrict__ WqT, short* __restrict__ WkT,
    short* __restrict__ WvT, short* __restrict__ WoT,
    const float* __restrict__ mask, float* __restrict__ padl2,
    const float* __restrict__ lq1, const float* __restrict__ lq2,
    const float* __restrict__ lk1, const float* __restrict__ lk2,
    float* __restrict__ lam) {
  __shared__ float t[32][33];
  const int bid = blockIdx.x;
  const int tid = threadIdx.x;

  if (bid < 12288) {  // ---- qkv f32 -> bf16 ----
    int i = bid * 256 + tid;
    const float4* src = (i < 1048576) ? q4 : ((i < 2097152) ? k4 : v4);
    float4 val = src[i & 1048575];
    short4 o;
    o.x = f2b(val.x); o.y = f2b(val.y); o.z = f2b(val.z); o.w = f2b(val.w);
    qkvb[i] = o;
    return;
  }
  if (bid < 20480) {  // ---- wconv: W[K][N] f32 -> Wt[N][K] bf16 ----
    int wq = bid - 12288;
    int z = wq >> 11, rem = wq & 2047;
    int nx = rem & 63, ky = rem >> 6;
    int N = (z < 2) ? 2048 : 1024;
    if (nx * 32 >= N) return;  // block-uniform
    const float* W = (z == 0) ? Wq : (z == 1) ? Wk : (z == 2) ? Wv : Wo;
    short* Wt = (z == 0) ? WqT : (z == 1) ? WkT : (z == 2) ? WvT : WoT;
    const int K = 1024;
    int n0 = nx * 32, k0 = ky * 32;
    int tx = tid & 31, ty = tid >> 5;
#pragma unroll
    for (int r = 0; r < 4; ++r)
      t[ty + r * 8][tx] = W[(size_t)(k0 + ty + r * 8) * N + n0 + tx];
    __syncthreads();
#pragma unroll
    for (int r = 0; r < 4; ++r)
      Wt[(size_t)(n0 + ty + r * 8) * K + k0 + tx] = f2b(t[tx][ty + r * 8]);
    return;
  }
  if (bid < 20496) {  // ---- padk ----
    int i = (bid - 20480) * 256 + tid;
    padl2[i] = (1.0f - mask[i]) * (-1.0e9f) * 1.44269504089f;
    return;
  }
  // ---- lambda scalar (wave 0 only) ----
  if (tid < 64) {
    float d1 = lq1[tid] * lk1[tid], d2 = lq2[tid] * lk2[tid];
#pragma unroll
    for (int x = 1; x < 64; x <<= 1) { d1 += __shfl_xor(d1, x); d2 += __shfl_xor(d2, x); }
    if (tid == 0) lam[0] = __expf(d1) - __expf(d2) + 0.8f;
  }
}

// ---- counted-vmcnt phase template: kk-split stage (2 chunks/thread/half) ----
#define STG(dst, srcp, kt, kk)                                                        \
  {                                                                                   \
    gl_lds16(srcp + (size_t)r0_ * 1024 + ((kt) << 6) + ((kk) << 5) + c0_,             \
             &dst[ch0_ << 3]);                                                        \
    gl_lds16(srcp + (size_t)r1_ * 1024 + ((kt) << 6) + ((kk) << 5) + c1_,             \
             &dst[ch1_ << 3]);                                                        \
  }

// ---------------- merged Q/K/V projection GEMMs, v3: counted-vmcnt phases ----------------
__global__ __launch_bounds__(256) void proj3(const short* __restrict__ Abase,
                                             const short* __restrict__ Btbase,
                                             short* __restrict__ QKout,
                                             short* __restrict__ Vtb) {
  __shared__ __align__(16) short As[2][2][128 * 32];
  __shared__ __align__(16) short Bs[2][2][128 * 32];
  const int bid = blockIdx.x;
  const int wk = (bid & 7) * 160 + (bid >> 3);  // bijective XCD chunk swizzle
  int z, my, nx;
  if (wk < 1024) { z = wk >> 9; int r = wk & 511; my = r >> 4; nx = r & 15; }
  else { z = 2; int r = wk - 1024; my = r >> 3; nx = r & 7; }

  const int tid = threadIdx.x;
  const int lane = tid & 63, w = tid >> 6;
  const int l15 = lane & 15, lhi = lane >> 4;
  const int wr = w >> 1, wc = w & 1;
  const int m0 = my * 128, n0 = nx * 128;

  const short* Ag = Abase + (size_t)z * 4194304 + (size_t)m0 * 1024;
  const short* Bg = Btbase + (size_t)z * 2097152 + (size_t)n0 * 1024;

  const int ch0_ = tid, ch1_ = tid + 256;
  const int r0_ = ch0_ >> 2, c0_ = (ch0_ & 3) << 3;
  const int r1_ = ch1_ >> 2, c1_ = (ch1_ & 3) << 3;

  f32x4 acc[4][4];
#pragma unroll
  for (int i = 0; i < 4; ++i)
#pragma unroll
    for (int j = 0; j < 4; ++j) acc[i][j] = (f32x4){0.f, 0.f, 0.f, 0.f};

  STG(As[0][0], Ag, 0, 0); STG(Bs[0][0], Bg, 0, 0);
  STG(As[0][1], Ag, 0, 1); STG(Bs[0][1], Bg, 0, 1);
  asm volatile("s_waitcnt vmcnt(4)" ::: "memory");
  __builtin_amdgcn_s_barrier();

  for (int kt = 0; kt < 16; ++kt) {
    const int buf = kt & 1;
#pragma unroll
    for (int kk = 0; kk < 2; ++kk) {
      const short* Ah = As[buf][kk];
      const short* Bh = Bs[buf][kk];
      bf16x8 af[4], bfr[4];
#pragma unroll
      for (int mi = 0; mi < 4; ++mi)
        af[mi] = *(const bf16x8*)&Ah[((wr * 64 + mi * 16 + l15) << 5) + (lhi << 3)];
#pragma unroll
      for (int ni = 0; ni < 4; ++ni)
        bfr[ni] = *(const bf16x8*)&Bh[((wc * 64 + ni * 16 + l15) << 5) + (lhi << 3)];
      if (kt < 15) {
        STG(As[buf ^ 1][kk], Ag, kt + 1, kk);
        STG(Bs[buf ^ 1][kk], Bg, kt + 1, kk);
      }
      __builtin_amdgcn_s_barrier();
      __builtin_amdgcn_s_setprio(1);
#pragma unroll
      for (int mi = 0; mi < 4; ++mi)
#pragma unroll
        for (int ni = 0; ni < 4; ++ni)
          acc[mi][ni] = __builtin_amdgcn_mfma_f32_16x16x32_bf16(af[mi], bfr[ni], acc[mi][ni], 0, 0, 0);
      __builtin_amdgcn_s_setprio(0);
      if (kt < 15) asm volatile("s_waitcnt vmcnt(4)" ::: "memory");
      else         asm volatile("s_waitcnt vmcnt(0)" ::: "memory");
      __builtin_amdgcn_s_barrier();
    }
  }

#pragma unroll
  for (int mi = 0; mi < 4; ++mi) {
#pragma unroll
    for (int ni = 0; ni < 4; ++ni) {
#pragma unroll
      for (int j = 0; j < 4; ++j) {
        int m = m0 + wr * 64 + mi * 16 + (lhi << 2) + j;
        int n = n0 + wc * 64 + ni * 16 + l15;
        float v = acc[mi][ni][j];
        int s = m & (SQ - 1), bb = m >> 11;
        if (z < 2) {
          int h = n >> 7, t = n & 127, path = t >> 6, tt = t & 63;
          (QKout + (size_t)z * 8388608)
              [((((size_t)(bb * NH + h) * 2 + path) * SQ + s) << 6) + tt] = f2b(v);
        } else {
          int h = n >> 6, t = n & 63;
          Vtb[(((size_t)(bb * NH + h) << 6) + t) * SQ + s] = f2b(v);
        }
      }
    }
  }
}

// ---------------- final GEMM, v3: counted-vmcnt phases ----------------
__global__ __launch_bounds__(256) void gemm_out(const short* __restrict__ A,
                                                const short* __restrict__ Bt,
                                                float* __restrict__ Cout) {
  __shared__ __align__(16) short As[2][2][128 * 32];
  __shared__ __align__(16) short Bs[2][2][128 * 32];
  const int bid = blockIdx.x;
  const int wk = (bid & 7) * 32 + (bid >> 3);
  const int my = wk >> 3, nx = wk & 7;

  const int tid = threadIdx.x;
  const int lane = tid & 63, w = tid >> 6;
  const int l15 = lane & 15, lhi = lane >> 4;
  const int wr = w >> 1, wc = w & 1;
  const int m0 = my * 128, n0 = nx * 128;

  const short* Ag = A + (size_t)m0 * 1024;
  const short* Bg = Bt + (size_t)n0 * 1024;

  const int ch0_ = tid, ch1_ = tid + 256;
  const int r0_ = ch0_ >> 2, c0_ = (ch0_ & 3) << 3;
  const int r1_ = ch1_ >> 2, c1_ = (ch1_ & 3) << 3;

  f32x4 acc[4][4];
#pragma unroll
  for (int i = 0; i < 4; ++i)
#pragma unroll
    for (int j = 0; j < 4; ++j) acc[i][j] = (f32x4){0.f, 0.f, 0.f, 0.f};

  STG(As[0][0], Ag, 0, 0); STG(Bs[0][0], Bg, 0, 0);
  STG(As[0][1], Ag, 0, 1); STG(Bs[0][1], Bg, 0, 1);
  asm volatile("s_waitcnt vmcnt(4)" ::: "memory");
  __builtin_amdgcn_s_barrier();

  for (int kt = 0; kt < 16; ++kt) {
    const int buf = kt & 1;
#pragma unroll
    for (int kk = 0; kk < 2; ++kk) {
      const short* Ah = As[buf][kk];
      const short* Bh = Bs[buf][kk];
      bf16x8 af[4], bfr[4];
#pragma unroll
      for (int mi = 0; mi < 4; ++mi)
        af[mi] = *(const bf16x8*)&Ah[((wr * 64 + mi * 16 + l15) << 5) + (lhi << 3)];
#pragma unroll
      for (int ni = 0; ni < 4; ++ni)
        bfr[ni] = *(const bf16x8*)&Bh[((wc * 64 + ni * 16 + l15) << 5) + (lhi << 3)];
      if (kt < 15) {
        STG(As[buf ^ 1][kk], Ag, kt + 1, kk);
        STG(Bs[buf ^ 1][kk], Bg, kt + 1, kk);
      }
      __builtin_amdgcn_s_barrier();
      __builtin_amdgcn_s_setprio(1);
#pragma unroll
      for (int mi = 0; mi < 4; ++mi)
#pragma unroll
        for (int ni = 0; ni < 4; ++ni)
          acc[mi][ni] = __builtin_amdgcn_mfma_f32_16x16x32_bf16(af[mi], bfr[ni], acc[mi][ni], 0, 0, 0);
      __builtin_amdgcn_s_setprio(0);
      if (kt < 15) asm volatile("s_waitcnt vmcnt(4)" ::: "memory");
      else         asm volatile("s_waitcnt vmcnt(0)" ::: "memory");
      __builtin_amdgcn_s_barrier();
    }
  }

#pragma unroll
  for (int mi = 0; mi < 4; ++mi)
#pragma unroll
    for (int ni = 0; ni < 4; ++ni)
#pragma unroll
      for (int j = 0; j < 4; ++j) {
        int m = m0 + wr * 64 + mi * 16 + (lhi << 2) + j;
        int n = n0 + wc * 64 + ni * 16 + l15;
        Cout[(size_t)m * 1024 + n] = acc[mi][ni][j];
      }
}

// ---------------- flash differential attention (v8 + bf16 attn store) ----------------
__global__ __launch_bounds__(256) void diff_attn(
    const short* __restrict__ Qp, const short* __restrict__ Kp,
    const short* __restrict__ Vt, const float* __restrict__ padl2,
    const float* __restrict__ lamp, short* __restrict__ attn,
    float* __restrict__ part) {
  __shared__ __align__(16) short K1s[2][64 * 64];
  __shared__ __align__(16) short K2s[2][64 * 64];
  __shared__ __align__(16) short Vts[2][64 * 64];
  __shared__ float red[8];

  const int bid = blockIdx.x;
  const int rk = bid >> 5, bh = bid & 31;
  const int qtA = 31 - rk, qtB = rk;
  const int ntA = qtA + 1, ntT = ntA + qtB + 1;
  const int b = bh >> 4, h = bh & 15;
  const int tid = threadIdx.x, lane = tid & 63, w = tid >> 6;
  const int l15 = lane & 15, lhi = lane >> 4;
  const int sw7 = l15 & 7;
  const int u0 = (lhi ^ sw7) << 3, u1 = ((4 + lhi) ^ sw7) << 3;

  const float L2E = 1.44269504089f;
  const float slope = exp2f(-0.5f * (float)(h + 1));
  const float SC = 0.125f * L2E;
  const float sl2 = slope * L2E;

  f32x4 ck[4];
#pragma unroll
  for (int cf = 0; cf < 4; ++cf)
#pragma unroll
    for (int j = 0; j < 4; ++j)
      ck[cf][j] = sl2 * (float)(16 * cf + 4 * lhi + j);

  const short* Q1g = Qp + (((size_t)bh * 2 + 0) * SQ) * DH;
  const short* Q2g = Qp + (((size_t)bh * 2 + 1) * SQ) * DH;
  const short* K1g = Kp + (((size_t)bh * 2 + 0) * SQ) * DH;
  const short* K2g = Kp + (((size_t)bh * 2 + 1) * SQ) * DH;
  const short* Vtg = Vt + (size_t)bh * DH * SQ;
  const float* padb = padl2 + (b << 11);

  int ucf[4];
#pragma unroll
  for (int cf = 0; cf < 4; ++cf)
    ucf[cf] = (((2 * cf + (lhi >> 1)) ^ sw7) << 1) + (lhi & 1);

  const int sidx0 = tid, sidx1 = 256 + tid;
  const int srow0 = sidx0 >> 3, sus0 = ((sidx0 & 7) ^ (srow0 & 7)) << 3;
  const int srow1 = sidx1 >> 3, sus1 = ((sidx1 & 7) ^ (srow1 & 7)) << 3;

#define STAGE(buf, k0s)                                                          \
  {                                                                              \
    gl_lds16(K1g + (size_t)((k0s) + srow0) * DH + sus0, &K1s[buf][sidx0 << 3]);  \
    gl_lds16(K2g + (size_t)((k0s) + srow0) * DH + sus0, &K2s[buf][sidx0 << 3]);  \
    gl_lds16(Vtg + (size_t)srow0 * SQ + (k0s) + sus0, &Vts[buf][sidx0 << 3]);    \
    gl_lds16(K1g + (size_t)((k0s) + srow1) * DH + sus1, &K1s[buf][sidx1 << 3]);  \
    gl_lds16(K2g + (size_t)((k0s) + srow1) * DH + sus1, &K2s[buf][sidx1 << 3]);  \
    gl_lds16(Vtg + (size_t)srow1 * SQ + (k0s) + sus1, &Vts[buf][sidx1 << 3]);    \
  }

  int cur = 0;
  int itg = 0;
  STAGE(0, 0);
  asm volatile("s_waitcnt vmcnt(0)" ::: "memory");
  __builtin_amdgcn_s_barrier();

  const float lamv = lamp[0];

  for (int ph = 0; ph < 2; ++ph) {
    const int qt = ph ? qtB : qtA;
    const int nt = qt + 1;
    const int wq0 = qt * 64 + (w << 4);
    const int q = wq0 + l15;
    const float qb8 = sl2 * (float)q + 8.0f;  // fixed max 8 (log2 domain)

    bf16x8 aq[2][2];
#pragma unroll
    for (int kk = 0; kk < 2; ++kk) {
      aq[0][kk] = *(const bf16x8*)&Q1g[(size_t)q * DH + kk * 32 + lhi * 8];
      aq[1][kk] = *(const bf16x8*)&Q2g[(size_t)q * DH + kk * 32 + lhi * 8];
    }
    f32x4 cq[4];
#pragma unroll
    for (int cf = 0; cf < 4; ++cf)
#pragma unroll
      for (int j = 0; j < 4; ++j) cq[cf][j] = ck[cf][j] - qb8;

    f32x4 acc[2][4];
    float ll[2] = {0.f, 0.f};
#pragma unroll
    for (int p = 0; p < 2; ++p)
#pragma unroll
      for (int i = 0; i < 4; ++i) acc[p][i] = (f32x4){0.f, 0.f, 0.f, 0.f};

    for (int kt = 0; kt < nt; ++kt, ++itg) {
      const int k0 = kt << 6;
      int g = itg + 1;
      if (g < ntT) {
        int k0n = ((g < ntA) ? g : g - ntA) << 6;
        STAGE(cur ^ 1, k0n);
      }

      const float t0 = sl2 * (float)k0;
      f32x4 base4[4];
#pragma unroll
      for (int cf = 0; cf < 4; ++cf) {
        f32x4 p4 = *(const f32x4*)&padb[k0 + 16 * cf + 4 * lhi];
#pragma unroll
        for (int j = 0; j < 4; ++j) base4[cf][j] = cq[cf][j] + (t0 + p4[j]);
      }
      const bool diag = (kt == nt - 1);

      u32x2 pa[2][4];
#pragma unroll
      for (int p = 0; p < 2; ++p) {
        const short* Ks = (p == 0) ? K1s[cur] : K2s[cur];
        f32x4 sv[4];
#pragma unroll
        for (int cf = 0; cf < 4; ++cf) {
          int rb = (cf * 16 + l15) << 6;
          f32x4 z = (f32x4){0.f, 0.f, 0.f, 0.f};
          bf16x8 ka = *(const bf16x8*)&Ks[rb + u0];
          bf16x8 kb = *(const bf16x8*)&Ks[rb + u1];
          sv[cf] = __builtin_amdgcn_mfma_f32_16x16x32_bf16(ka, aq[p][0], z, 0, 0, 0);
          sv[cf] = __builtin_amdgcn_mfma_f32_16x16x32_bf16(kb, aq[p][1], sv[cf], 0, 0, 0);
        }
        float rsum = 0.f;
#pragma unroll
        for (int cf = 0; cf < 4; ++cf) {
          float pv[4];
#pragma unroll
          for (int j = 0; j < 4; ++j) pv[j] = sv[cf][j] * SC + base4[cf][j];
          if (diag) {
#pragma unroll
            for (int j = 0; j < 4; ++j) {
              int kc = k0 + 16 * cf + 4 * lhi + j;
              pv[j] = (kc > q) ? -1.0e9f : pv[j];
            }
          }
          float e0 = exp2f(pv[0]);
          float e1 = exp2f(pv[1]);
          float e2 = exp2f(pv[2]);
          float e3 = exp2f(pv[3]);
          rsum += (e0 + e1) + (e2 + e3);
          pa[p][cf][0] = cvt_pk(e0, e1);
          pa[p][cf][1] = cvt_pk(e2, e3);
        }
        ll[p] += rsum;
      }

      // PV: A = P (register-resident), B = V^T b64 fragments
#pragma unroll
      for (int df = 0; df < 4; ++df) {
        const u32x2* vrow = (const u32x2*)&Vts[cur][(df * 16 + l15) << 6];
#pragma unroll
        for (int cf = 0; cf < 4; ++cf) {
          u32x2 vb = vrow[ucf[cf]];
          acc[0][df] = mfma16(pa[0][cf], vb, acc[0][df]);
          acc[1][df] = mfma16(pa[1][cf], vb, acc[1][df]);
        }
      }

      asm volatile("s_waitcnt vmcnt(0)" ::: "memory");
      __builtin_amdgcn_s_barrier();
      cur ^= 1;
    }

#pragma unroll
    for (int p = 0; p < 2; ++p) {
      ll[p] += __shfl_xor(ll[p], 16);
      ll[p] += __shfl_xor(ll[p], 32);
    }
    float li1 = 1.0f / ll[0], li2 = lamv / ll[1];
    float li1b[4], li2b[4];
#pragma unroll
    for (int j = 0; j < 4; ++j) {
      li1b[j] = __shfl(li1, (lhi << 2) + j);
      li2b[j] = __shfl(li2, (lhi << 2) + j);
    }
    float lsum = 0.f, lsq = 0.f;
#pragma unroll
    for (int df = 0; df < 4; ++df)
#pragma unroll
      for (int j = 0; j < 4; ++j) {
        int qq = wq0 + (lhi << 2) + j;
        float o = acc[0][df][j] * li1b[j] - acc[1][df][j] * li2b[j];
        attn[((size_t)b * SQ + qq) * HIDN + (h << 6) + (df << 4) + l15] = f2b(o);
        lsum += o; lsq += o * o;  // stats from unrounded f32 (unchanged)
      }
#pragma unroll
    for (int x = 1; x < 64; x <<= 1) {
      lsum += __shfl_xor(lsum, x);
      lsq += __shfl_xor(lsq, x);
    }
    if (lane == 0) { red[w] = lsum; red[4 + w] = lsq; }
    __syncthreads();
    if (tid == 0) {
      part[((size_t)bh * 32 + qt) * 2] = red[0] + red[1] + red[2] + red[3];
      part[((size_t)bh * 32 + qt) * 2 + 1] = red[4] + red[5] + red[6] + red[7];
    }
  }
#undef STAGE
}

// ---------------- GN stats + apply -> bf16 X (bf16 attn input) ----------------
__global__ __launch_bounds__(256) void gn_apply(const short* __restrict__ attn,
                                                const float* __restrict__ part,
                                                const float* __restrict__ gnw,
                                                const float* __restrict__ gnb,
                                                short* __restrict__ X) {
  __shared__ float smean[16], sinv[16];
  const int r = blockIdx.x;            // 0..4095 row of [B*SQ][1024]
  const int tid = threadIdx.x;
  const int bh_base = (r >> 11) << 4;  // 16 consecutive bh for this row

  {
    int grp = tid >> 5, i = tid & 31;  // 8 groups of 32 lanes
#pragma unroll
    for (int rep = 0; rep < 2; ++rep) {
      int bhl = grp + rep * 8;
      float s = part[((size_t)(bh_base + bhl) * 32 + i) * 2];
      float ss = part[((size_t)(bh_base + bhl) * 32 + i) * 2 + 1];
#pragma unroll
      for (int x = 1; x < 32; x <<= 1) { s += __shfl_xor(s, x); ss += __shfl_xor(ss, x); }
      if (i == 0) {
        float n = (float)(SQ * DH);
        float mean = s / n;
        float var = ss / n - mean * mean;
        smean[bhl] = mean;
        sinv[bhl] = rsqrtf(var + 1e-5f);
      }
    }
  }
  __syncthreads();

  size_t base = ((size_t)r << 10) + ((size_t)tid << 2);
  int c = tid << 2;
  int bhl = c >> 6;
  float mean = smean[bhl], inv = sinv[bhl];
  short4 a = *(const short4*)&attn[base];
  short4 o;
  o.x = f2b(((b2f(a.x) - mean) * inv * gnw[c + 0] + gnb[c + 0]) * 0.2f);
  o.y = f2b(((b2f(a.y) - mean) * inv * gnw[c + 1] + gnb[c + 1]) * 0.2f);
  o.z = f2b(((b2f(a.z) - mean) * inv * gnw[c + 2] + gnb[c + 2]) * 0.2f);
  o.w = f2b(((b2f(a.w) - mean) * inv * gnw[c + 3] + gnb[c + 3]) * 0.2f);
  *(short4*)&X[base] = o;
}

extern "C" void kernel_launch(void* const* d_in, const int* in_sizes, int n_in,
                              void* d_out, int out_size, void* d_ws, size_t ws_size,
                              hipStream_t stream) {
  const float* query = (const float*)d_in[0];
  const float* key = (const float*)d_in[1];
  const float* value = (const float*)d_in[2];
  const float* mask = (const float*)d_in[3];
  const float* Wq = (const float*)d_in[4];
  const float* Wk = (const float*)d_in[5];
  const float* Wv = (const float*)d_in[6];
  const float* Wo = (const float*)d_in[7];
  const float* lq1 = (const float*)d_in[8];
  const float* lq2 = (const float*)d_in[9];
  const float* lk1 = (const float*)d_in[10];
  const float* lk2 = (const float*)d_in[11];
  const float* gnw = (const float*)d_in[12];
  const float* gnb = (const float*)d_in[13];

  char* ws = (char*)d_ws;
  short* WqT = (short*)(ws + 0);          //  4 MiB   (WqT,WkT,WvT contiguous)
  short* WkT = (short*)(ws + 4194304);
  short* WvT = (short*)(ws + 8388608);
  short* WoT = (short*)(ws + 10485760);   //  2 MiB
  short* qb = (short*)(ws + 12582912);    //  8 MiB (qb,kb,vb contiguous)
  short* Qp = (short*)(ws + 37748736);    // 16 MiB (Qp,Kp contiguous)
  short* Kp = (short*)(ws + 54525952);
  short* Vtb = (short*)(ws + 71303168);   //  8 MiB
  short* attn = (short*)(ws + 12582912);  //  8 MiB bf16, overlays qb (dead after proj3)
  short* X = (short*)(ws + 29360128);     //  8 MiB, overlays vb
  float* part = (float*)(ws + 79691776);  // 16 KiB
  float* lam = (float*)(ws + 79708416);   //  4 B
  float* padl2 = (float*)(ws + 79708672); // 16 KiB

  prep<<<dim3(20497), 256, 0, stream>>>(
      (const float4*)query, (const float4*)key, (const float4*)value, (short4*)qb,
      Wq, Wk, Wv, Wo, WqT, WkT, WvT, WoT, mask, padl2, lq1, lq2, lk1, lk2, lam);

  proj3<<<dim3(1280), 256, 0, stream>>>(qb, WqT, Qp, Vtb);

  diff_attn<<<dim3(512), 256, 0, stream>>>(Qp, Kp, Vtb, padl2, lam, attn, part);
  gn_apply<<<4096, 256, 0, stream>>>(attn, part, gnw, gnb, X);
  gemm_out<<<dim3(256), 256, 0, stream>>>(X, WoT, (float*)d_out);
}